// Round 5
// baseline (235.324 us; speedup 1.0000x reference)
//
#include <hip/hip_runtime.h>

// GATLayer on MI355X — round 16.
//   r15 post-mortem: gemm_out latency-serialized: grid 256 = 1 block/CU,
//   per-iter barrier lockstep, 2 waves/SIMD -> 5475 cyc/iter vs 1024 MFMA
//   demand (MfmaUtil 19%, VALU 50%, occ 19%). FETCH fixed (16.6 MB).
//   r16 gemm_out: split m 2x -> block 256o x 128m (acc[4]), grid 512 =
//   2 independent blocks/CU (anti-phase barriers), 16 waves/CU. am/bm
//   pre-splatted to half8 outside K-loop (guarantees pk lowering).
//   Staging/swizzle identical to r15. z: waves 0-3 own strips 0-3.
//   wmh/prep/gemm_y unchanged.

constexpr int B = 32, C = 512, N = 1024, O = 512;
constexpr float L2E = 1.4426950408889634f;

typedef _Float16 half8 __attribute__((ext_vector_type(8)));
typedef _Float16 half4v __attribute__((ext_vector_type(4)));
typedef _Float16 half2v __attribute__((ext_vector_type(2)));
typedef float f32x4 __attribute__((ext_vector_type(4)));
typedef float f32x16 __attribute__((ext_vector_type(16)));

#if __has_builtin(__builtin_amdgcn_exp2f)
#define EXP2(x) __builtin_amdgcn_exp2f(x)
#else
#define EXP2(x) exp2f(x)
#endif

__device__ __forceinline__ half8 cvt8(float4 a, float4 b) {
  half8 h;
  h[0] = (_Float16)a.x; h[1] = (_Float16)a.y; h[2] = (_Float16)a.z; h[3] = (_Float16)a.w;
  h[4] = (_Float16)b.x; h[5] = (_Float16)b.y; h[6] = (_Float16)b.z; h[7] = (_Float16)b.w;
  return h;
}

__device__ __forceinline__ unsigned fenc(float x) {
  unsigned u = __float_as_uint(x);
  return (u & 0x80000000u) ? ~u : (u ^ 0x80000000u);
}
__device__ __forceinline__ float fdec(unsigned e) {
  unsigned u = (e & 0x80000000u) ? (e ^ 0x80000000u) : ~e;
  return __uint_as_float(u);
}

// direct global->LDS DMA, 16B per lane; lds dest must be wave-uniform base
__device__ __forceinline__ void gload16(const _Float16* g, _Float16* l) {
  __builtin_amdgcn_global_load_lds(
      (const __attribute__((address_space(1))) unsigned int*)(g),
      (__attribute__((address_space(3))) unsigned int*)(l), 16, 0, 0);
}

// z accumulation: f32 += sum of 8 halfs (consistent with MFMA af values)
__device__ __forceinline__ float dot8z(half8 a, float c) {
#if __has_builtin(__builtin_amdgcn_fdot2)
  half2v one2; one2[0] = (_Float16)1.0f; one2[1] = (_Float16)1.0f;
  c = __builtin_amdgcn_fdot2(__builtin_shufflevector(a, a, 0, 1), one2, c, false);
  c = __builtin_amdgcn_fdot2(__builtin_shufflevector(a, a, 2, 3), one2, c, false);
  c = __builtin_amdgcn_fdot2(__builtin_shufflevector(a, a, 4, 5), one2, c, false);
  c = __builtin_amdgcn_fdot2(__builtin_shufflevector(a, a, 6, 7), one2, c, false);
#else
#pragma unroll
  for (int j = 0; j < 8; ++j) c += (float)a[j];
#endif
  return c;
}

// ---------------- K0: wm -> fp16 (once) + qmax_u init ----------------
__global__ __launch_bounds__(256) void wmh_kernel(const float* __restrict__ wm,
                                                  _Float16* __restrict__ wmh,
                                                  unsigned* __restrict__ qmax_u) {
  int i = (blockIdx.x * 256 + threadIdx.x) * 8;
  float4 a = *(const float4*)(wm + i);
  float4 b = *(const float4*)(wm + i + 4);
  *(half8*)(wmh + i) = cvt8(a, b);
  if (blockIdx.x == 0 && threadIdx.x < 64) qmax_u[threadIdx.x] = 0u;  // fenc-min
}

// ---------------- K0b: prep — x -> xhT[b][n][c] fp16 + q,k (L2E-scaled) + qmax
// grid (N/64, B), 256 thr. Each block: 64 n rows, all C, 8 chunks of 64 c.
__global__ __launch_bounds__(256) void prep_kernel(const float* __restrict__ x,
    const float* __restrict__ wq, const float* __restrict__ wk,
    float* __restrict__ q, float* __restrict__ k, unsigned* __restrict__ qmax_u,
    _Float16* __restrict__ xhT) {
  __shared__ half2v Ts[32 * 67];   // 8576 B; reused as float scratch for q/k red
  int b  = blockIdx.y;
  int n0 = blockIdx.x * 64;
  int t = threadIdx.x;
  int cp = t >> 3;                 // c-pair 0..31 within 64-c chunk
  int ng = t & 7;                  // 8 n per thread
  const float* xbase = x + ((size_t)b * C + 2 * cp) * N + n0 + ng * 8;
  int nl = t >> 2;                 // 0..63: n row for transpose-out
  int hq = t & 3;                  // 16-half c-quarter
  _Float16* xout = xhT + ((size_t)b * N + n0 + nl) * C + hq * 16;
  float aq[8] = {}, ak[8] = {};

  for (int ch = 0; ch < 8; ++ch) {
    int c0 = ch * 64;
    const float* xr = xbase + (size_t)c0 * N;
    float4 a0 = *(const float4*)(xr);
    float4 a1 = *(const float4*)(xr + 4);
    float4 b0 = *(const float4*)(xr + N);
    float4 b1 = *(const float4*)(xr + N + 4);
    float2 wq2 = *(const float2*)&wq[c0 + 2 * cp];
    float2 wk2 = *(const float2*)&wk[c0 + 2 * cp];
    aq[0] = fmaf(wq2.x, a0.x, fmaf(wq2.y, b0.x, aq[0]));
    aq[1] = fmaf(wq2.x, a0.y, fmaf(wq2.y, b0.y, aq[1]));
    aq[2] = fmaf(wq2.x, a0.z, fmaf(wq2.y, b0.z, aq[2]));
    aq[3] = fmaf(wq2.x, a0.w, fmaf(wq2.y, b0.w, aq[3]));
    aq[4] = fmaf(wq2.x, a1.x, fmaf(wq2.y, b1.x, aq[4]));
    aq[5] = fmaf(wq2.x, a1.y, fmaf(wq2.y, b1.y, aq[5]));
    aq[6] = fmaf(wq2.x, a1.z, fmaf(wq2.y, b1.z, aq[6]));
    aq[7] = fmaf(wq2.x, a1.w, fmaf(wq2.y, b1.w, aq[7]));
    ak[0] = fmaf(wk2.x, a0.x, fmaf(wk2.y, b0.x, ak[0]));
    ak[1] = fmaf(wk2.x, a0.y, fmaf(wk2.y, b0.y, ak[1]));
    ak[2] = fmaf(wk2.x, a0.z, fmaf(wk2.y, b0.z, ak[2]));
    ak[3] = fmaf(wk2.x, a0.w, fmaf(wk2.y, b0.w, ak[3]));
    ak[4] = fmaf(wk2.x, a1.x, fmaf(wk2.y, b1.x, ak[4]));
    ak[5] = fmaf(wk2.x, a1.y, fmaf(wk2.y, b1.y, ak[5]));
    ak[6] = fmaf(wk2.x, a1.z, fmaf(wk2.y, b1.z, ak[6]));
    ak[7] = fmaf(wk2.x, a1.w, fmaf(wk2.y, b1.w, ak[7]));
    {
      half2v* xp = &Ts[cp * 67 + ng * 8];
      xp[0] = half2v{(_Float16)a0.x, (_Float16)b0.x};
      xp[1] = half2v{(_Float16)a0.y, (_Float16)b0.y};
      xp[2] = half2v{(_Float16)a0.z, (_Float16)b0.z};
      xp[3] = half2v{(_Float16)a0.w, (_Float16)b0.w};
      xp[4] = half2v{(_Float16)a1.x, (_Float16)b1.x};
      xp[5] = half2v{(_Float16)a1.y, (_Float16)b1.y};
      xp[6] = half2v{(_Float16)a1.z, (_Float16)b1.z};
      xp[7] = half2v{(_Float16)a1.w, (_Float16)b1.w};
    }
    __syncthreads();
    // transpose-out: thread -> row nl, c-halfs [hq*16, hq*16+16)
    half8 o0h, o1h;
#pragma unroll
    for (int u = 0; u < 4; ++u) {
      half2v pr = Ts[(hq * 8 + u) * 67 + nl];
      o0h[2 * u] = pr[0]; o0h[2 * u + 1] = pr[1];
    }
#pragma unroll
    for (int u = 4; u < 8; ++u) {
      half2v pr = Ts[(hq * 8 + u) * 67 + nl];
      o1h[2 * (u - 4)] = pr[0]; o1h[2 * (u - 4) + 1] = pr[1];
    }
    *(half8*)(xout + c0)     = o0h;
    *(half8*)(xout + c0 + 8) = o1h;
    __syncthreads();
  }

  // q/k reduction over 32 c-pair groups (reuse Ts as float scratch, stride 67)
  float* red = (float*)Ts;
#pragma unroll
  for (int j = 0; j < 8; ++j) red[cp * 67 + ng * 8 + j] = aq[j];
  __syncthreads();
  float qv = -1e30f;
  if (t < 64) {
    float s = 0.f;
#pragma unroll
    for (int p = 0; p < 32; ++p) s += red[p * 67 + t];
    qv = L2E * s;
    q[b * N + n0 + t] = qv;
  }
  __syncthreads();
#pragma unroll
  for (int j = 0; j < 8; ++j) red[cp * 67 + ng * 8 + j] = ak[j];
  __syncthreads();
  if (t < 64) {
    float s = 0.f;
#pragma unroll
    for (int p = 0; p < 32; ++p) s += red[p * 67 + t];
    k[b * N + n0 + t] = L2E * s;
    float m = qv;
#pragma unroll
    for (int off = 32; off > 0; off >>= 1) m = fmaxf(m, __shfl_down(m, off, 64));
    if (t == 0) atomicMax(&qmax_u[b], fenc(m));
  }
}

// ---------------- K1: gemm_y — Yt[b][o][n] = wmh[o,:] . xhT[n,:]  (fp16 MFMA)
// 128n x 128o tile, 256 thr (2x2 waves of 64n x 64o), K=512 in 16 steps of 32.
// A (xhT rows) staged via global_load_lds into dbuf LDS; B (wmh) direct-global.
__global__ __launch_bounds__(256) void gemm_y_kernel(const _Float16* __restrict__ xhT,
    const _Float16* __restrict__ wmh, _Float16* __restrict__ Yt) {
  __shared__ __align__(16) _Float16 As[2][128 * 32];  // 8 KB per buffer
  int f = blockIdx.x;
  int xcd = f & 7, g = f >> 3;
  int o_id = g & 3;                        // fastest within XCD stream
  int p2 = xcd * 32 + (g >> 2);            // 0..255 tile id
  int n_id = p2 & 7, b = p2 >> 3;
  int n0 = n_id * 128, o0 = o_id * 128;
  int t = threadIdx.x;
  int w = t >> 6, l = t & 63;
  int nw = w >> 1, ow = w & 1;
  int lm = l & 15, q8 = (l >> 4) * 8, q4 = (l >> 4) * 4;

  // staging source: instr m covers LDS bytes [m*4096 + w*1024 + lane*16)
  const _Float16* asrc[2];
#pragma unroll
  for (int m = 0; m < 2; ++m) {
    int u = m * 256 + t;                   // row = u>>2, col halfs = (u&3)*8
    asrc[m] = xhT + ((size_t)b * N + n0 + (u >> 2)) * C + (u & 3) * 8;
  }
  const _Float16* wb[4];
#pragma unroll
  for (int j = 0; j < 4; ++j)
    wb[j] = wmh + (size_t)(o0 + ow * 64 + j * 16 + lm) * C + q8;

  // prologue: stage K-step 0 into buf 0
#pragma unroll
  for (int m = 0; m < 2; ++m)
    gload16(asrc[m], &As[0][(m * 256 + (t & ~63)) * 8]);
  __syncthreads();  // compiler drains vmcnt(0) before s_barrier

  f32x4 acc[4][4] = {};
  for (int it = 0; it < 16; ++it) {
    int p = it & 1;
    if (it < 15) {  // stage next K-step; stays in flight across the MFMA block
      int c1 = (it + 1) * 32;
#pragma unroll
      for (int m = 0; m < 2; ++m)
        gload16(asrc[m] + c1, &As[p ^ 1][(m * 256 + (t & ~63)) * 8]);
    }
    int c0 = it * 32;
    half8 bf[4];
#pragma unroll
    for (int j = 0; j < 4; ++j) bf[j] = *(const half8*)(wb[j] + c0);
#pragma unroll
    for (int i = 0; i < 4; ++i) {
      half8 af = *(const half8*)&As[p][(nw * 64 + i * 16 + lm) * 32 + q8];
#pragma unroll
      for (int j = 0; j < 4; ++j)
        acc[i][j] = __builtin_amdgcn_mfma_f32_16x16x32_f16(af, bf[j], acc[i][j], 0, 0, 0);
    }
    __syncthreads();  // single barrier: drains stage(p^1); all reads of p done
  }

#pragma unroll
  for (int i = 0; i < 4; ++i) {
    int n_b = n0 + nw * 64 + i * 16 + q4;
#pragma unroll
    for (int j = 0; j < 4; ++j) {
      int o_c = o0 + ow * 64 + j * 16 + lm;
      half4v h;
      h[0] = (_Float16)acc[i][j][0];
      h[1] = (_Float16)acc[i][j][1];
      h[2] = (_Float16)acc[i][j][2];
      h[3] = (_Float16)acc[i][j][3];
      *(half4v*)&Yt[((size_t)b * O + o_c) * N + n_b] = h;
    }
  }
}

// ---------------- K2: gemm_out — o-split waves, Y slab LDS-staged, m-split 2x.
// Block 512 thr = 8 waves; wave w owns o-rows [o0+32w,+32) x 128 m (acc[4]).
// Grid 512 flat XCD-grouped (8 m-blocks per (b,o) slab per XCD) = 2 blocks/CU.
__global__ __launch_bounds__(512, 4) void gemm_out_kernel(const _Float16* __restrict__ Yt,
    const float* __restrict__ q, const float* __restrict__ k,
    const unsigned* __restrict__ qmax_u, const float* __restrict__ bm,
    float* __restrict__ out) {
  __shared__ __align__(16) _Float16 us[N];           // 2 KB  exp2(qv)
  __shared__ __align__(16) _Float16 vs[N];           // 2 KB  exp2(0.01*qv)
  __shared__ __align__(16) _Float16 Ys[2][256 * 32]; // 2 x 16 KB  Y slab
  __shared__ float izs[128];
  int f = blockIdx.x;
  int xcd = f & 7, g = f >> 3;
  int m_id = g & 7;                        // fastest: 8 m-blocks share (b,o)
  int pair = xcd * 8 + (g >> 3);           // 0..63
  int o_id = pair & 1, b = pair >> 1;
  int o0 = o_id * 256, m0 = m_id * 128;
  int t = threadIdx.x;
  int w = t >> 6, l = t & 63;
  int ml = l & 31, g2 = l >> 5;
  int fx = (ml >> 1) & 3;                  // read-side chunk-xor key

  // stage u/v (per n) into LDS
  {
    float2 q2 = *(const float2*)&q[b * N + t * 2];
    us[t * 2]     = (_Float16)EXP2(q2.x);
    us[t * 2 + 1] = (_Float16)EXP2(q2.y);
    vs[t * 2]     = (_Float16)EXP2(0.01f * q2.x);
    vs[t * 2 + 1] = (_Float16)EXP2(0.01f * q2.y);
  }
  // per-lane m-row constants for the 4 m-strips, pre-splatted to half8
  float qmv = fdec(qmax_u[b]);
  half8 am8[4], bm8[4];
#pragma unroll
  for (int s = 0; s < 4; ++s) {
    float km = k[b * N + m0 + s * 32 + ml];
    float s0 = qmv + km;
    float M = fmaxf(s0, 0.01f * s0);
    _Float16 a = (_Float16)EXP2(km - M);
    _Float16 bb = (_Float16)EXP2(fmaf(0.01f, km, -M));
#pragma unroll
    for (int j = 0; j < 8; ++j) { am8[s][j] = a; bm8[s][j] = bb; }
  }

  // staging: slab it = 256 rows x 64 B (n in [32it,32it+32)).
  // LDS slot u (0..1023) = byte 16u: row = u>>2, lds_chunk = u&3.
  // content = global chunk (lds_chunk ^ ((row>>1)&3))  [rule 21 involution]
  const _Float16* ysb = Yt + ((size_t)b * O + o0) * N;
  const _Float16* src0;
  const _Float16* src1;
  {
    int u0 = t,      r0 = u0 >> 2, cg0 = (u0 & 3) ^ ((r0 >> 1) & 3);
    int u1 = 512 + t, r1 = u1 >> 2, cg1 = (u1 & 3) ^ ((r1 >> 1) & 3);
    src0 = ysb + (size_t)r0 * N + cg0 * 8;
    src1 = ysb + (size_t)r1 * N + cg1 * 8;
  }
  int ldsbase0 = (t & ~63) * 8;            // halfs; +512*8 for second instr

  // prologue: stage slab 0
  gload16(src0, &Ys[0][ldsbase0]);
  gload16(src1, &Ys[0][4096 + ldsbase0]);
  __syncthreads();  // us/vs + slab 0 (compiler drains vmcnt before barrier)

  f32x16 acc[4] = {};
  float zacc = 0.f;
  for (int it = 0; it < N / 32; ++it) {
    int p = it & 1;
    if (it < N / 32 - 1) {  // stage next slab; in flight across MFMA body
      int c1 = (it + 1) * 32;
      gload16(src0 + c1, &Ys[p ^ 1][ldsbase0]);
      gload16(src1 + c1, &Ys[p ^ 1][4096 + ldsbase0]);
    }
    const _Float16* yb = &Ys[p][(w * 32 + ml) * 32];  // this lane's o-row
#pragma unroll
    for (int kh = 0; kh < 2; ++kh) {
      half8 u8 = *(const half8*)&us[it * 32 + kh * 16 + g2 * 8];
      half8 v8 = *(const half8*)&vs[it * 32 + kh * 16 + g2 * 8];
      half8 bf = *(const half8*)&yb[((kh * 2 + g2) ^ fx) * 8];
#pragma unroll
      for (int s = 0; s < 4; ++s) {
        half8 af = __builtin_elementwise_max(u8 * am8[s], v8 * bm8[s]);
        if (w == s) zacc = dot8z(af, zacc);   // waves 0-3 own strips 0-3
        acc[s] = __builtin_amdgcn_mfma_f32_32x32x16_f16(af, bf, acc[s], 0, 0, 0);
      }
    }
    __syncthreads();  // reads of p done; stage(p^1) drained
  }

  // z: lane (ml,g2) of wave w<4 holds sum over its g2-half of n for row w*32+ml
  if (w < 4) {
    float zt = zacc + __shfl_xor(zacc, 32, 64);
    if (l < 32) izs[w * 32 + l] = 1.0f / zt;
  }
  __syncthreads();

  // D: col(o) = l&31 per lane; row(m) = s*32 + (reg&3)+8*(reg>>2)+4*g2
  int o_c = o0 + w * 32 + ml;
  float bias = bm[o_c];
  float* orow = out + ((size_t)b * O + o_c) * N + m0;
#pragma unroll
  for (int s = 0; s < 4; ++s) {
#pragma unroll
    for (int rq = 0; rq < 4; ++rq) {
      float4 izv = *(const float4*)&izs[s * 32 + 8 * rq + 4 * g2];
      int m_b = s * 32 + 8 * rq + 4 * g2;
      float4 r;
      r.x = fmaxf(fmaf(acc[s][rq * 4 + 0], izv.x, bias), 0.f);
      r.y = fmaxf(fmaf(acc[s][rq * 4 + 1], izv.y, bias), 0.f);
      r.z = fmaxf(fmaf(acc[s][rq * 4 + 2], izv.z, bias), 0.f);
      r.w = fmaxf(fmaf(acc[s][rq * 4 + 3], izv.w, bias), 0.f);
      *(float4*)&orow[m_b] = r;
    }
  }
}

extern "C" void kernel_launch(void* const* d_in, const int* in_sizes, int n_in,
                              void* d_out, int out_size, void* d_ws, size_t ws_size,
                              hipStream_t stream) {
  const float* x  = (const float*)d_in[0];
  const float* wq = (const float*)d_in[1];
  const float* wk = (const float*)d_in[2];
  const float* wm = (const float*)d_in[3];
  const float* bm = (const float*)d_in[4];
  float* out = (float*)d_out;

  // ws: q[B*N] | k[B*N] | qmax_u[64] | wmh[O*C] f16 | Yt[B*O*N] f16  (~33 MiB)
  float* q    = (float*)d_ws;
  float* k    = q + B * N;
  unsigned* qmax_u = (unsigned*)(k + B * N);
  _Float16* wmh = (_Float16*)(qmax_u + 64);
  _Float16* Yt  = wmh + (size_t)O * C;
  // xhT[b][n][c] fp16 (32 MiB) lives in d_out's first half: fully written by
  // prep, consumed by gemm_y, dead before gemm_out overwrites out.
  _Float16* xhT = (_Float16*)d_out;

  wmh_kernel<<<dim3(O * C / (256 * 8)), 256, 0, stream>>>(wm, wmh, qmax_u);
  prep_kernel<<<dim3(N / 64, B), 256, 0, stream>>>(x, wq, wk, q, k, qmax_u, xhT);
  gemm_y_kernel<<<dim3(1024), 256, 0, stream>>>(xhT, wmh, Yt);
  gemm_out_kernel<<<dim3(512), 512, 0, stream>>>(Yt, q, k, qmax_u, bm, out);
}

// Round 6
// 209.668 us; speedup vs baseline: 1.1224x; 1.1224x over previous
//
#include <hip/hip_runtime.h>

// GATLayer on MI355X — round 17.
//   r16 post-mortem: occupancy was NOT gemm_out's limiter (2 blk/CU: 81 us,
//   worse). All gemm_out restructures (r13/14/15/16) lost to the plain
//   r11/r12 version (54-57 us, measured twice) -> revert to it.
//   Wall arithmetic across r11-r16: wall - sum(dur) ~= 25 us PER KERNEL
//   boundary (75 us @3 kernels, ~97 us @4). This round cuts a boundary:
//   - wmh folded into prep (blockIdx.x==0 blocks convert wm slices).
//   - qmax_u deleted: gemm_out computes qmax in-block from the q row it
//     already loads (bitwise-same max), removing the atomic+init ordering.
//   - gemm_out = r12 verbatim except qmv source.
//   3 kernels: prep -> gemm_y -> gemm_out.

constexpr int B = 32, C = 512, N = 1024, O = 512;
constexpr float L2E = 1.4426950408889634f;

typedef _Float16 half8 __attribute__((ext_vector_type(8)));
typedef _Float16 half4v __attribute__((ext_vector_type(4)));
typedef _Float16 half2v __attribute__((ext_vector_type(2)));
typedef float f32x4 __attribute__((ext_vector_type(4)));
typedef float f32x16 __attribute__((ext_vector_type(16)));

#if __has_builtin(__builtin_amdgcn_exp2f)
#define EXP2(x) __builtin_amdgcn_exp2f(x)
#else
#define EXP2(x) exp2f(x)
#endif

__device__ __forceinline__ half8 cvt8(float4 a, float4 b) {
  half8 h;
  h[0] = (_Float16)a.x; h[1] = (_Float16)a.y; h[2] = (_Float16)a.z; h[3] = (_Float16)a.w;
  h[4] = (_Float16)b.x; h[5] = (_Float16)b.y; h[6] = (_Float16)b.z; h[7] = (_Float16)b.w;
  return h;
}

// direct global->LDS DMA, 16B per lane; lds dest must be wave-uniform base
__device__ __forceinline__ void gload16(const _Float16* g, _Float16* l) {
  __builtin_amdgcn_global_load_lds(
      (const __attribute__((address_space(1))) unsigned int*)(g),
      (__attribute__((address_space(3))) unsigned int*)(l), 16, 0, 0);
}

// ---------------- K0: prep — x -> xhT[b][n][c] fp16 + q,k (L2E-scaled)
//                          + wm -> wmh fp16 (folded, blockIdx.x==0 blocks)
// grid (N/64, B), 256 thr. Each block: 64 n rows, all C, 8 chunks of 64 c.
__global__ __launch_bounds__(256) void prep_kernel(const float* __restrict__ x,
    const float* __restrict__ wq, const float* __restrict__ wk,
    const float* __restrict__ wm,
    float* __restrict__ q, float* __restrict__ k,
    _Float16* __restrict__ wmh, _Float16* __restrict__ xhT) {
  __shared__ half2v Ts[32 * 67];   // 8576 B; reused as float scratch for q/k red
  int b  = blockIdx.y;
  int n0 = blockIdx.x * 64;
  int t = threadIdx.x;

  // folded wm conversion: 32 blocks (x==0), each does a 8192-float slice
  if (blockIdx.x == 0) {
    const float* wsrc = wm + b * 8192;
    _Float16* wdst = wmh + b * 8192;
#pragma unroll
    for (int j = 0; j < 4; ++j) {
      int i = j * 2048 + t * 8;
      float4 a = *(const float4*)(wsrc + i);
      float4 bb = *(const float4*)(wsrc + i + 4);
      *(half8*)(wdst + i) = cvt8(a, bb);
    }
  }

  int cp = t >> 3;                 // c-pair 0..31 within 64-c chunk
  int ng = t & 7;                  // 8 n per thread
  const float* xbase = x + ((size_t)b * C + 2 * cp) * N + n0 + ng * 8;
  int nl = t >> 2;                 // 0..63: n row for transpose-out
  int hq = t & 3;                  // 16-half c-quarter
  _Float16* xout = xhT + ((size_t)b * N + n0 + nl) * C + hq * 16;
  float aq[8] = {}, ak[8] = {};

  for (int ch = 0; ch < 8; ++ch) {
    int c0 = ch * 64;
    const float* xr = xbase + (size_t)c0 * N;
    float4 a0 = *(const float4*)(xr);
    float4 a1 = *(const float4*)(xr + 4);
    float4 b0 = *(const float4*)(xr + N);
    float4 b1 = *(const float4*)(xr + N + 4);
    float2 wq2 = *(const float2*)&wq[c0 + 2 * cp];
    float2 wk2 = *(const float2*)&wk[c0 + 2 * cp];
    aq[0] = fmaf(wq2.x, a0.x, fmaf(wq2.y, b0.x, aq[0]));
    aq[1] = fmaf(wq2.x, a0.y, fmaf(wq2.y, b0.y, aq[1]));
    aq[2] = fmaf(wq2.x, a0.z, fmaf(wq2.y, b0.z, aq[2]));
    aq[3] = fmaf(wq2.x, a0.w, fmaf(wq2.y, b0.w, aq[3]));
    aq[4] = fmaf(wq2.x, a1.x, fmaf(wq2.y, b1.x, aq[4]));
    aq[5] = fmaf(wq2.x, a1.y, fmaf(wq2.y, b1.y, aq[5]));
    aq[6] = fmaf(wq2.x, a1.z, fmaf(wq2.y, b1.z, aq[6]));
    aq[7] = fmaf(wq2.x, a1.w, fmaf(wq2.y, b1.w, aq[7]));
    ak[0] = fmaf(wk2.x, a0.x, fmaf(wk2.y, b0.x, ak[0]));
    ak[1] = fmaf(wk2.x, a0.y, fmaf(wk2.y, b0.y, ak[1]));
    ak[2] = fmaf(wk2.x, a0.z, fmaf(wk2.y, b0.z, ak[2]));
    ak[3] = fmaf(wk2.x, a0.w, fmaf(wk2.y, b0.w, ak[3]));
    ak[4] = fmaf(wk2.x, a1.x, fmaf(wk2.y, b1.x, ak[4]));
    ak[5] = fmaf(wk2.x, a1.y, fmaf(wk2.y, b1.y, ak[5]));
    ak[6] = fmaf(wk2.x, a1.z, fmaf(wk2.y, b1.z, ak[6]));
    ak[7] = fmaf(wk2.x, a1.w, fmaf(wk2.y, b1.w, ak[7]));
    {
      half2v* xp = &Ts[cp * 67 + ng * 8];
      xp[0] = half2v{(_Float16)a0.x, (_Float16)b0.x};
      xp[1] = half2v{(_Float16)a0.y, (_Float16)b0.y};
      xp[2] = half2v{(_Float16)a0.z, (_Float16)b0.z};
      xp[3] = half2v{(_Float16)a0.w, (_Float16)b0.w};
      xp[4] = half2v{(_Float16)a1.x, (_Float16)b1.x};
      xp[5] = half2v{(_Float16)a1.y, (_Float16)b1.y};
      xp[6] = half2v{(_Float16)a1.z, (_Float16)b1.z};
      xp[7] = half2v{(_Float16)a1.w, (_Float16)b1.w};
    }
    __syncthreads();
    // transpose-out: thread -> row nl, c-halfs [hq*16, hq*16+16)
    half8 o0h, o1h;
#pragma unroll
    for (int u = 0; u < 4; ++u) {
      half2v pr = Ts[(hq * 8 + u) * 67 + nl];
      o0h[2 * u] = pr[0]; o0h[2 * u + 1] = pr[1];
    }
#pragma unroll
    for (int u = 4; u < 8; ++u) {
      half2v pr = Ts[(hq * 8 + u) * 67 + nl];
      o1h[2 * (u - 4)] = pr[0]; o1h[2 * (u - 4) + 1] = pr[1];
    }
    *(half8*)(xout + c0)     = o0h;
    *(half8*)(xout + c0 + 8) = o1h;
    __syncthreads();
  }

  // q/k reduction over 32 c-pair groups (reuse Ts as float scratch, stride 67)
  float* red = (float*)Ts;
#pragma unroll
  for (int j = 0; j < 8; ++j) red[cp * 67 + ng * 8 + j] = aq[j];
  __syncthreads();
  if (t < 64) {
    float s = 0.f;
#pragma unroll
    for (int p = 0; p < 32; ++p) s += red[p * 67 + t];
    q[b * N + n0 + t] = L2E * s;
  }
  __syncthreads();
#pragma unroll
  for (int j = 0; j < 8; ++j) red[cp * 67 + ng * 8 + j] = ak[j];
  __syncthreads();
  if (t < 64) {
    float s = 0.f;
#pragma unroll
    for (int p = 0; p < 32; ++p) s += red[p * 67 + t];
    k[b * N + n0 + t] = L2E * s;
  }
}

// ---------------- K1: gemm_y — Yt[b][o][n] = wmh[o,:] . xhT[n,:]  (fp16 MFMA)
// 128n x 128o tile, 256 thr (2x2 waves of 64n x 64o), K=512 in 16 steps of 32.
// A (xhT rows) staged via global_load_lds into dbuf LDS; B (wmh) direct-global.
__global__ __launch_bounds__(256) void gemm_y_kernel(const _Float16* __restrict__ xhT,
    const _Float16* __restrict__ wmh, _Float16* __restrict__ Yt) {
  __shared__ __align__(16) _Float16 As[2][128 * 32];  // 8 KB per buffer
  int f = blockIdx.x;
  int xcd = f & 7, g = f >> 3;
  int o_id = g & 3;                        // fastest within XCD stream
  int p2 = xcd * 32 + (g >> 2);            // 0..255 tile id
  int n_id = p2 & 7, b = p2 >> 3;
  int n0 = n_id * 128, o0 = o_id * 128;
  int t = threadIdx.x;
  int w = t >> 6, l = t & 63;
  int nw = w >> 1, ow = w & 1;
  int lm = l & 15, q8 = (l >> 4) * 8, q4 = (l >> 4) * 4;

  // staging source: instr m covers LDS bytes [m*4096 + w*1024 + lane*16)
  const _Float16* asrc[2];
#pragma unroll
  for (int m = 0; m < 2; ++m) {
    int u = m * 256 + t;                   // row = u>>2, col halfs = (u&3)*8
    asrc[m] = xhT + ((size_t)b * N + n0 + (u >> 2)) * C + (u & 3) * 8;
  }
  const _Float16* wb[4];
#pragma unroll
  for (int j = 0; j < 4; ++j)
    wb[j] = wmh + (size_t)(o0 + ow * 64 + j * 16 + lm) * C + q8;

  // prologue: stage K-step 0 into buf 0
#pragma unroll
  for (int m = 0; m < 2; ++m)
    gload16(asrc[m], &As[0][(m * 256 + (t & ~63)) * 8]);
  __syncthreads();  // compiler drains vmcnt(0) before s_barrier

  f32x4 acc[4][4] = {};
  for (int it = 0; it < 16; ++it) {
    int p = it & 1;
    if (it < 15) {  // stage next K-step; stays in flight across the MFMA block
      int c1 = (it + 1) * 32;
#pragma unroll
      for (int m = 0; m < 2; ++m)
        gload16(asrc[m] + c1, &As[p ^ 1][(m * 256 + (t & ~63)) * 8]);
    }
    int c0 = it * 32;
    half8 bf[4];
#pragma unroll
    for (int j = 0; j < 4; ++j) bf[j] = *(const half8*)(wb[j] + c0);
#pragma unroll
    for (int i = 0; i < 4; ++i) {
      half8 af = *(const half8*)&As[p][(nw * 64 + i * 16 + lm) * 32 + q8];
#pragma unroll
      for (int j = 0; j < 4; ++j)
        acc[i][j] = __builtin_amdgcn_mfma_f32_16x16x32_f16(af, bf[j], acc[i][j], 0, 0, 0);
    }
    __syncthreads();  // single barrier: drains stage(p^1); all reads of p done
  }

#pragma unroll
  for (int i = 0; i < 4; ++i) {
    int n_b = n0 + nw * 64 + i * 16 + q4;
#pragma unroll
    for (int j = 0; j < 4; ++j) {
      int o_c = o0 + ow * 64 + j * 16 + lm;
      half4v h;
      h[0] = (_Float16)acc[i][j][0];
      h[1] = (_Float16)acc[i][j][1];
      h[2] = (_Float16)acc[i][j][2];
      h[3] = (_Float16)acc[i][j][3];
      *(half4v*)&Yt[((size_t)b * O + o_c) * N + n_b] = h;
    }
  }
}

// ---------------- K2: gemm_out — r12 verbatim (measured 54-57 us) except
// qmax computed in-block from the q row this block already loads.
// 32x32x16 MFMA, block 256o x 256m, 512 thr, dbuf Ys, 1 barrier/slab.
__global__ __launch_bounds__(512) void gemm_out_kernel(const _Float16* __restrict__ Yt,
    const float* __restrict__ q, const float* __restrict__ k,
    const float* __restrict__ bm, float* __restrict__ out) {
  __shared__ __align__(16) float qs[N];             // 4 KB
  __shared__ __align__(16) _Float16 Ys[2][256 * 40];// 40 KB
  __shared__ float izs[256];
  __shared__ float mred[8];
  int b  = blockIdx.y;
  int o0 = blockIdx.x * 256;
  int m0 = blockIdx.z * 256;
  int t = threadIdx.x;
  int w = t >> 6, l = t & 63;
  int ml = l & 31, g2 = l >> 5;

  float2 q2 = *(const float2*)&q[b * N + t * 2];
  *(float2*)&qs[t * 2] = q2;
  // in-block qmax over the full q row (same floats the atomic path maxed)
  float lmax = fmaxf(q2.x, q2.y);
#pragma unroll
  for (int off = 32; off > 0; off >>= 1) lmax = fmaxf(lmax, __shfl_down(lmax, off, 64));
  if (l == 0) mred[w] = lmax;

  float km = k[b * N + m0 + w * 32 + ml];   // issue load pre-barrier

  half8 ones;
#pragma unroll
  for (int jj = 0; jj < 8; ++jj) ones[jj] = (_Float16)1.0f;
  f32x16 acc_z = {};
  int yr = t >> 1, yp = t & 1;
  const _Float16* ysrc = Yt + ((size_t)b * O + o0 + yr) * N + yp * 16;

  // prologue: stage slab 0
  {
    half8 z0 = *(const half8*)(ysrc);
    half8 z1 = *(const half8*)(ysrc + 8);
    *(half8*)&Ys[0][yr * 40 + yp * 16]     = z0;
    *(half8*)&Ys[0][yr * 40 + yp * 16 + 8] = z1;
  }
  __syncthreads();  // qs + mred + slab 0

  float qmv = mred[0];
#pragma unroll
  for (int j = 1; j < 8; ++j) qmv = fmaxf(qmv, mred[j]);
  float s0 = qmv + km;
  float M  = fmaxf(s0, 0.01f * s0);
  float kc2 = km - M;
  float kc3 = fmaf(0.01f, km, -M);

  f32x16 acc[8] = {};
  for (int it = 0; it < N / 32; ++it) {
    int p = it & 1;
    int n0k = it * 32;
    half8 z0, z1;
    if (it < N / 32 - 1) {  // prefetch next slab; drains after the MFMA body
      z0 = *(const half8*)(ysrc + n0k + 32);
      z1 = *(const half8*)(ysrc + n0k + 40);
    }
#pragma unroll
    for (int kh = 0; kh < 2; ++kh) {
      float4 qa = *(const float4*)&qs[n0k + kh * 16 + g2 * 8];
      float4 qb = *(const float4*)&qs[n0k + kh * 16 + g2 * 8 + 4];
      float qv[8] = {qa.x, qa.y, qa.z, qa.w, qb.x, qb.y, qb.z, qb.w};
      half8 af;
#pragma unroll
      for (int jj = 0; jj < 8; ++jj) {
        float arg = fmaxf(qv[jj] + kc2, fmaf(0.01f, qv[jj], kc3));
        af[jj] = (_Float16)EXP2(arg);
      }
      acc_z = __builtin_amdgcn_mfma_f32_32x32x16_f16(af, ones, acc_z, 0, 0, 0);
#pragma unroll
      for (int s = 0; s < 8; ++s) {
        half8 bf = *(const half8*)&Ys[p][(s * 32 + ml) * 40 + kh * 16 + g2 * 8];
        acc[s] = __builtin_amdgcn_mfma_f32_32x32x16_f16(af, bf, acc[s], 0, 0, 0);
      }
    }
    if (it < N / 32 - 1) {
      *(half8*)&Ys[p ^ 1][yr * 40 + yp * 16]     = z0;
      *(half8*)&Ys[p ^ 1][yr * 40 + yp * 16 + 8] = z1;
    }
    __syncthreads();  // single barrier: p reads + p^1 writes complete
  }

  // acc_z D: row = (reg&3) + 8*(reg>>2) + 4*g2, col = l&31 (all cols equal)
  if (ml == 0) {
#pragma unroll
    for (int rq = 0; rq < 4; ++rq)
#pragma unroll
      for (int r = 0; r < 4; ++r)
        izs[w * 32 + r + 8 * rq + 4 * g2] = 1.0f / acc_z[rq * 4 + r];
  }
  __syncthreads();

  float4 izv[4];
#pragma unroll
  for (int rq = 0; rq < 4; ++rq)
    izv[rq] = *(const float4*)&izs[w * 32 + 8 * rq + 4 * g2];

  // s outer: per o-row, the rq stores are adjacent (write-combine)
#pragma unroll
  for (int s = 0; s < 8; ++s) {
    int o_c = o0 + s * 32 + ml;
    float bias = bm[o_c];
#pragma unroll
    for (int rq = 0; rq < 4; ++rq) {
      int m_b = m0 + w * 32 + 8 * rq + 4 * g2;
      float4 r;
      r.x = fmaxf(fmaf(acc[s][rq * 4 + 0], izv[rq].x, bias), 0.f);
      r.y = fmaxf(fmaf(acc[s][rq * 4 + 1], izv[rq].y, bias), 0.f);
      r.z = fmaxf(fmaf(acc[s][rq * 4 + 2], izv[rq].z, bias), 0.f);
      r.w = fmaxf(fmaf(acc[s][rq * 4 + 3], izv[rq].w, bias), 0.f);
      *(float4*)&out[((size_t)b * O + o_c) * N + m_b] = r;
    }
  }
}

extern "C" void kernel_launch(void* const* d_in, const int* in_sizes, int n_in,
                              void* d_out, int out_size, void* d_ws, size_t ws_size,
                              hipStream_t stream) {
  const float* x  = (const float*)d_in[0];
  const float* wq = (const float*)d_in[1];
  const float* wk = (const float*)d_in[2];
  const float* wm = (const float*)d_in[3];
  const float* bm = (const float*)d_in[4];
  float* out = (float*)d_out;

  // ws: q[B*N] | k[B*N] | pad | wmh[O*C] f16 | Yt[B*O*N] f16  (~33 MiB)
  float* q    = (float*)d_ws;
  float* k    = q + B * N;
  _Float16* wmh = (_Float16*)(k + B * N + 64);
  _Float16* Yt  = wmh + (size_t)O * C;
  // xhT[b][n][c] fp16 (32 MiB) lives in d_out's first half: fully written by
  // prep, consumed by gemm_y, dead before gemm_out overwrites out.
  _Float16* xhT = (_Float16*)d_out;

  prep_kernel<<<dim3(N / 64, B), 256, 0, stream>>>(x, wq, wk, wm, q, k, wmh, xhT);
  gemm_y_kernel<<<dim3(1024), 256, 0, stream>>>(xhT, wmh, Yt);
  gemm_out_kernel<<<dim3(O / 256, B, N / 256), 512, 0, stream>>>(Yt, q, k, bm, out);
}